// Round 1
// baseline (276.197 us; speedup 1.0000x reference)
//
#include <hip/hip_runtime.h>
#include <stdint.h>
#include <stddef.h>

// ---------------------------------------------------------------------------
// SelfAttention (B=2, T=2048, D=1024, H=16, hd=64), outputs: out fp32 [B,T,D]
// then att fp32 [B,H,T,T]. Internals in bf16 MFMA (16x16x32), softmax fp32.
// ---------------------------------------------------------------------------

typedef __attribute__((ext_vector_type(8))) short short8;   // 8 x bf16
typedef __attribute__((ext_vector_type(4))) float f32x4;

#define LDS_AS __attribute__((address_space(3)))
#define GLB_AS __attribute__((address_space(1)))

static __device__ __forceinline__ unsigned short f2bf(float f) {
  union { float f; uint32_t u; } v; v.f = f;
  uint32_t u = v.u;
  return (unsigned short)((u + 0x7fffu + ((u >> 16) & 1u)) >> 16);  // RNE
}

static __device__ __forceinline__ void gload16(const void* g, void* l) {
  // 16B per lane, LDS dest = wave-uniform base + lane*16 (we pass base+lane*16
  // so firstlane sees the base). Global source is per-lane (pre-swizzled).
  __builtin_amdgcn_global_load_lds((const GLB_AS uint32_t*)g, (LDS_AS uint32_t*)l, 16, 0, 0);
}

static __device__ __forceinline__ f32x4 mfma16(short8 a, short8 b, f32x4 c) {
  return __builtin_amdgcn_mfma_f32_16x16x32_bf16(a, b, c, 0, 0, 0);
}

// ---------------------------------------------------------------------------
// small converters
// ---------------------------------------------------------------------------
__global__ void k_convert_x(const float* __restrict__ x, unsigned short* __restrict__ xb) {
  int i = blockIdx.x * 256 + threadIdx.x;               // 4096 blocks: 4M elems /4
  float4 v = ((const float4*)x)[i];
  ushort4 o;
  o.x = f2bf(v.x); o.y = f2bf(v.y); o.z = f2bf(v.z); o.w = f2bf(v.w);
  ((ushort4*)xb)[i] = o;
}

__global__ void k_mask(const int* __restrict__ m, float* __restrict__ madd) {
  int i = blockIdx.x * 256 + threadIdx.x;               // 16 blocks: 4096 elems
  madd[i] = m[i] ? -1e9f : 0.0f;
}

// transpose-convert: wt[n][k] = bf16(w[k][n]); 4 weights, 1024x1024 each.
__global__ void k_transpose_w(const float* __restrict__ w0, const float* __restrict__ w1,
                              const float* __restrict__ w2, const float* __restrict__ w3,
                              unsigned short* __restrict__ o0, unsigned short* __restrict__ o1,
                              unsigned short* __restrict__ o2, unsigned short* __restrict__ o3) {
  int bx = blockIdx.x;
  int which = bx >> 8, tile = bx & 255;
  const float* w = which == 0 ? w0 : which == 1 ? w1 : which == 2 ? w2 : w3;
  unsigned short* o = which == 0 ? o0 : which == 1 ? o1 : which == 2 ? o2 : o3;
  int k0 = (tile >> 4) << 6, n0 = (tile & 15) << 6;
  __shared__ float t[64][65];
  int tid = threadIdx.x;
  int r = tid >> 4, c4 = (tid & 15) << 2;
#pragma unroll
  for (int i = 0; i < 4; i++) {
    int row = r + (i << 4);
    float4 v = *(const float4*)(w + (size_t)(k0 + row) * 1024 + n0 + c4);
    t[row][c4] = v.x; t[row][c4 + 1] = v.y; t[row][c4 + 2] = v.z; t[row][c4 + 3] = v.w;
  }
  __syncthreads();
#pragma unroll
  for (int i = 0; i < 4; i++) {
    int n = r + (i << 4);
    ushort4 ov;
    ov.x = f2bf(t[c4 + 0][n]); ov.y = f2bf(t[c4 + 1][n]);
    ov.z = f2bf(t[c4 + 2][n]); ov.w = f2bf(t[c4 + 3][n]);
    *(ushort4*)(o + (size_t)(n0 + n) * 1024 + k0 + c4) = ov;
  }
}

// ---------------------------------------------------------------------------
// GEMM core: C[128x128] = A[m0:,:1024] * Bt[n0:,:1024]^T, bf16 in, fp32 acc.
// A: [M][1024] row-major bf16; Bt: [N][1024] row-major bf16 (= W^T).
// 256 threads = 4 waves in 2x2; each wave 64x64 = 4x4 frags of 16x16x32.
// LDS tiles [128][64] bf16, XOR-swizzled (granule ^= row&7) to kill the
// 128B-row-stride bank conflict (G4); swizzle applied on the *global source*
// of global_load_lds (m173 pattern) and on the ds_read address.
// ---------------------------------------------------------------------------
static __device__ __forceinline__ void gemm_tile(const unsigned short* __restrict__ A,
                                                 const unsigned short* __restrict__ Bt,
                                                 int m0, int n0,
                                                 f32x4 acc[4][4], char* ldsA, char* ldsB) {
  const int tid = threadIdx.x;
  const int l = tid & 63;
  const int wr = tid >> 7;            // wave row (0..1)
  const int wc = (tid >> 6) & 1;      // wave col (0..1)
  const int arow0 = wr * 64 + (l & 15);
  const int brow0 = wc * 64 + (l & 15);
  const int srow = tid >> 3;          // staging: 0..31 per call-group
  const int sgi = tid & 7;            // 16B granule within 128B row

  for (int kt = 0; kt < 1024; kt += 64) {
    __syncthreads();
#pragma unroll
    for (int c = 0; c < 4; c++) {
      int row = c * 32 + srow;
      int soff = (sgi ^ (row & 7)) << 3;   // swizzled elem offset in row
      gload16(A + (size_t)(m0 + row) * 1024 + kt + soff, ldsA + (c * 256 + tid) * 16);
      gload16(Bt + (size_t)(n0 + row) * 1024 + kt + soff, ldsB + (c * 256 + tid) * 16);
    }
    asm volatile("s_waitcnt vmcnt(0)" ::: "memory");
    __syncthreads();
#pragma unroll
    for (int ks = 0; ks < 2; ks++) {
      const int kbyte = ks * 64 + ((l >> 4) << 4);
      short8 a[4], b[4];
#pragma unroll
      for (int i = 0; i < 4; i++) {
        int row = arow0 + i * 16;
        a[i] = *(const short8*)(ldsA + row * 128 + (kbyte ^ ((row & 7) << 4)));
      }
#pragma unroll
      for (int j = 0; j < 4; j++) {
        int row = brow0 + j * 16;
        b[j] = *(const short8*)(ldsB + row * 128 + (kbyte ^ ((row & 7) << 4)));
      }
#pragma unroll
      for (int i = 0; i < 4; i++)
#pragma unroll
        for (int j = 0; j < 4; j++)
          acc[i][j] = mfma16(a[i], b[j], acc[i][j]);
    }
  }
}

// Fused Q/K/V projection. grid = (32, 24): y -> {mat 0..2} x {nblock 0..7}.
// Q,K written bf16 as [b,h,t,d]; V written bf16 transposed as [b,h,d,t].
__global__ __launch_bounds__(256) void k_gemm_qkv(const unsigned short* __restrict__ xb,
    const unsigned short* __restrict__ wqt, const unsigned short* __restrict__ wkt,
    const unsigned short* __restrict__ wvt,
    const float* __restrict__ bq, const float* __restrict__ bk, const float* __restrict__ bv,
    unsigned short* __restrict__ Q, unsigned short* __restrict__ K, unsigned short* __restrict__ Vt) {
  __shared__ __align__(16) char smem[32768];
  char* ldsA = smem;
  char* ldsB = smem + 16384;
  const int mat = blockIdx.y >> 3;
  const int nb = blockIdx.y & 7;
  const unsigned short* Bt = mat == 0 ? wqt : mat == 1 ? wkt : wvt;
  const float* bias = mat == 0 ? bq : mat == 1 ? bk : bv;
  const int m0 = blockIdx.x * 128, n0 = nb * 128;

  f32x4 acc[4][4] = {};
  gemm_tile(xb, Bt, m0, n0, acc, ldsA, ldsB);

  const int tid = threadIdx.x, l = tid & 63;
  const int wr = tid >> 7, wc = (tid >> 6) & 1;
  if (mat < 2) {
    unsigned short* O = (mat == 0) ? Q : K;
#pragma unroll
    for (int j = 0; j < 4; j++) {
      int col = n0 + wc * 64 + j * 16 + (l & 15);
      float bv_ = bias[col];
      int h = col >> 6, d = col & 63;
#pragma unroll
      for (int i = 0; i < 4; i++) {
        int row0 = m0 + wr * 64 + i * 16 + ((l >> 4) << 2);
#pragma unroll
        for (int e = 0; e < 4; e++) {
          int row = row0 + e;
          int b = row >> 11, t = row & 2047;
          O[(((size_t)(b * 16 + h)) * 2048 + t) * 64 + d] = f2bf(acc[i][j][e] + bv_);
        }
      }
    }
  } else {
#pragma unroll
    for (int j = 0; j < 4; j++) {
      int col = n0 + wc * 64 + j * 16 + (l & 15);
      float bv_ = bias[col];
      int h = col >> 6, d = col & 63;
#pragma unroll
      for (int i = 0; i < 4; i++) {
        int row0 = m0 + wr * 64 + i * 16 + ((l >> 4) << 2);
        int b = row0 >> 11, t0 = row0 & 2047;
        ushort4 pk;
        pk.x = f2bf(acc[i][j][0] + bv_);
        pk.y = f2bf(acc[i][j][1] + bv_);
        pk.z = f2bf(acc[i][j][2] + bv_);
        pk.w = f2bf(acc[i][j][3] + bv_);
        *(ushort4*)(Vt + ((size_t)(b * 16 + h) * 64 + d) * 2048 + t0) = pk;
      }
    }
  }
}

// Output projection: out fp32 [4096][1024] = ctx(bf16) @ wp + bp. grid (32,8).
__global__ __launch_bounds__(256) void k_gemm_proj(const unsigned short* __restrict__ ctx,
    const unsigned short* __restrict__ wpt, const float* __restrict__ bp,
    float* __restrict__ out) {
  __shared__ __align__(16) char smem[32768];
  char* ldsA = smem;
  char* ldsB = smem + 16384;
  const int m0 = blockIdx.x * 128, n0 = blockIdx.y * 128;
  f32x4 acc[4][4] = {};
  gemm_tile(ctx, wpt, m0, n0, acc, ldsA, ldsB);
  const int tid = threadIdx.x, l = tid & 63;
  const int wr = tid >> 7, wc = (tid >> 6) & 1;
#pragma unroll
  for (int j = 0; j < 4; j++) {
    int col = n0 + wc * 64 + j * 16 + (l & 15);
    float bv_ = bp[col];
#pragma unroll
    for (int i = 0; i < 4; i++) {
      int row0 = m0 + wr * 64 + i * 16 + ((l >> 4) << 2);
#pragma unroll
      for (int e = 0; e < 4; e++)
        out[(size_t)(row0 + e) * 1024 + col] = acc[i][j][e] + bv_;
    }
  }
}

// ---------------------------------------------------------------------------
// Fused attention. grid = B*H*32 (=1024); block 256 (4 waves).
// Block handles 64 q-rows of one (b,h). Wave w owns q-rows [w*16, w*16+16).
// Pass A: stream K in 128-key chunks, online (max,sum) per row (chunk-max
//         trick: 1 exp/elem + 2 exp/row/chunk). Cross-lane reduce at end.
// Pass B: re-stream K + V, p = exp(l-m)/s, write att fp32 to d_out, stage p
//         bf16 into swizzled LDS, PV-MFMA into O; O -> ctx bf16.
// Q [b,h,t,d], K [b,h,t,d], Vt [b,h,d,t] all bf16.
// ---------------------------------------------------------------------------
__global__ __launch_bounds__(256) void k_attn(const unsigned short* __restrict__ Q,
    const unsigned short* __restrict__ K, const unsigned short* __restrict__ Vt,
    const float* __restrict__ maskadd, float* __restrict__ att,
    unsigned short* __restrict__ ctx) {
  __shared__ __align__(16) char smem[57344];
  char* Ql = smem;              //  8 KB: [64][64] bf16, swizzled (128B rows)
  char* Kl = smem + 8192;       // 16 KB: [128][64] bf16, swizzled (128B rows)
  char* Vl = smem + 24576;      // 16 KB: [64][128] bf16, swizzled (256B rows)
  char* Pl = smem + 40960;      // 16 KB: [64][128] bf16, swizzled (256B rows)

  const int bid = blockIdx.x;
  const int qb = bid & 31, bh = bid >> 5;
  const int b = bh >> 4, h = bh & 15;
  const int tid = threadIdx.x, w = tid >> 6, l = tid & 63;
  const int qbase = qb * 64;

  const unsigned short* Qg = Q + (size_t)bh * 2048 * 64;
  const unsigned short* Kg = K + (size_t)bh * 2048 * 64;
  const unsigned short* Vg = Vt + (size_t)bh * 64 * 2048;
  const float* mg = maskadd + b * 2048;
  const float scale = 0.125f;   // 1/sqrt(64)

  // ---- stage Q block (rows qbase..qbase+63) ----
#pragma unroll
  for (int c = 0; c < 2; c++) {
    int g = c * 256 + tid;
    int row = g >> 3, gi = tid & 7;
    gload16(Qg + (size_t)(qbase + row) * 64 + ((gi ^ (row & 7)) << 3), Ql + g * 16);
  }
  asm volatile("s_waitcnt vmcnt(0)" ::: "memory");
  __syncthreads();

  short8 qf[2];
  {
    int row = w * 16 + (l & 15);
#pragma unroll
    for (int ks = 0; ks < 2; ks++) {
      int kbyte = ks * 64 + ((l >> 4) << 4);
      qf[ks] = *(const short8*)(Ql + row * 128 + (kbyte ^ ((row & 7) << 4)));
    }
  }

  float mrow[4], srow[4];
#pragma unroll
  for (int e = 0; e < 4; e++) { mrow[e] = -1e30f; srow[e] = 0.0f; }

  // ---- pass A: online max/sum ----
  for (int ch = 0; ch < 16; ch++) {
    __syncthreads();
#pragma unroll
    for (int c = 0; c < 4; c++) {
      int g = c * 256 + tid;
      int row = g >> 3, gi = tid & 7;
      gload16(Kg + (size_t)(ch * 128 + row) * 64 + ((gi ^ (row & 7)) << 3), Kl + g * 16);
    }
    asm volatile("s_waitcnt vmcnt(0)" ::: "memory");
    __syncthreads();

    float lv[8][4];
    float cmax[4] = {-1e30f, -1e30f, -1e30f, -1e30f};
#pragma unroll
    for (int nt = 0; nt < 8; nt++) {
      f32x4 s = {};
#pragma unroll
      for (int ks = 0; ks < 2; ks++) {
        int row = nt * 16 + (l & 15);
        int kbyte = ks * 64 + ((l >> 4) << 4);
        short8 kf = *(const short8*)(Kl + row * 128 + (kbyte ^ ((row & 7) << 4)));
        s = mfma16(qf[ks], kf, s);
      }
      int key = ch * 128 + nt * 16 + (l & 15);
      float madd = mg[key];
#pragma unroll
      for (int e = 0; e < 4; e++) {
        lv[nt][e] = s[e] * scale + madd;
        cmax[e] = fmaxf(cmax[e], lv[nt][e]);
      }
    }
#pragma unroll
    for (int e = 0; e < 4; e++) {
      float cs = 0.0f;
#pragma unroll
      for (int nt = 0; nt < 8; nt++) cs += __expf(lv[nt][e] - cmax[e]);
      float mn = fmaxf(mrow[e], cmax[e]);
      srow[e] = srow[e] * __expf(mrow[e] - mn) + cs * __expf(cmax[e] - mn);
      mrow[e] = mn;
    }
  }

  // ---- reduce (m,s) across the 16 lanes holding the same rows ----
  float invs[4];
#pragma unroll
  for (int e = 0; e < 4; e++) {
    float m = mrow[e], s = srow[e];
#pragma unroll
    for (int msk = 1; msk < 16; msk <<= 1) {
      float mo = __shfl_xor(m, msk);
      float so = __shfl_xor(s, msk);
      float mn = fmaxf(m, mo);
      s = s * __expf(m - mn) + so * __expf(mo - mn);
      m = mn;
    }
    mrow[e] = m;
    invs[e] = 1.0f / s;
  }

  // ---- pass B: att + PV ----
  f32x4 o[4] = {};
  for (int ch = 0; ch < 16; ch++) {
    __syncthreads();
#pragma unroll
    for (int c = 0; c < 4; c++) {
      int g = c * 256 + tid;
      int row = g >> 3, gi = tid & 7;
      gload16(Kg + (size_t)(ch * 128 + row) * 64 + ((gi ^ (row & 7)) << 3), Kl + g * 16);
    }
#pragma unroll
    for (int c = 0; c < 4; c++) {
      int g = c * 256 + tid;
      int d = g >> 4, gi = tid & 15;
      gload16(Vg + (size_t)d * 2048 + ch * 128 + ((gi ^ (d & 7)) << 3), Vl + g * 16);
    }
    asm volatile("s_waitcnt vmcnt(0)" ::: "memory");
    __syncthreads();

#pragma unroll
    for (int nt = 0; nt < 8; nt++) {
      f32x4 s = {};
#pragma unroll
      for (int ks = 0; ks < 2; ks++) {
        int row = nt * 16 + (l & 15);
        int kbyte = ks * 64 + ((l >> 4) << 4);
        short8 kf = *(const short8*)(Kl + row * 128 + (kbyte ^ ((row & 7) << 4)));
        s = mfma16(qf[ks], kf, s);
      }
      int key = ch * 128 + nt * 16 + (l & 15);
      float madd = mg[key];
#pragma unroll
      for (int e = 0; e < 4; e++) {
        float p = __expf(s[e] * scale + madd - mrow[e]) * invs[e];
        int qrow = qbase + w * 16 + ((l >> 4) << 2) + e;
        att[((size_t)bh * 2048 + qrow) * 2048 + key] = p;
        int pr = w * 16 + ((l >> 4) << 2) + e;
        int cb = (nt * 16 + (l & 15)) * 2;
        *(unsigned short*)(Pl + pr * 256 + (cb ^ ((pr & 7) << 4))) = f2bf(p);
      }
    }
    // PV: O[16 x 64] += P[16 x 128] * V[128 x 64]   (per wave)
#pragma unroll
    for (int ks = 0; ks < 4; ks++) {
      int prow = w * 16 + (l & 15);
      int kbyte = ks * 64 + ((l >> 4) << 4);
      short8 pa = *(const short8*)(Pl + prow * 256 + (kbyte ^ ((prow & 7) << 4)));
#pragma unroll
      for (int dt = 0; dt < 4; dt++) {
        int vrow = dt * 16 + (l & 15);
        short8 vb = *(const short8*)(Vl + vrow * 256 + (kbyte ^ ((vrow & 7) << 4)));
        o[dt] = mfma16(pa, vb, o[dt]);
      }
    }
  }

  // ---- epilogue: ctx bf16 [b][t][h*64+d] ----
#pragma unroll
  for (int dt = 0; dt < 4; dt++) {
#pragma unroll
    for (int e = 0; e < 4; e++) {
      int t = qbase + w * 16 + ((l >> 4) << 2) + e;
      int col = h * 64 + dt * 16 + (l & 15);
      ctx[((size_t)(b * 2048 + t)) * 1024 + col] = f2bf(o[dt][e]);
    }
  }
}

// ---------------------------------------------------------------------------
extern "C" void kernel_launch(void* const* d_in, const int* in_sizes, int n_in,
                              void* d_out, int out_size, void* d_ws, size_t ws_size,
                              hipStream_t stream) {
  const float* x  = (const float*)d_in[0];
  const int* mask = (const int*)d_in[1];
  const float* wq = (const float*)d_in[2];
  const float* bq = (const float*)d_in[3];
  const float* wk = (const float*)d_in[4];
  const float* bk = (const float*)d_in[5];
  const float* wv = (const float*)d_in[6];
  const float* bv = (const float*)d_in[7];
  const float* wp = (const float*)d_in[8];
  const float* bp = (const float*)d_in[9];

  float* out = (float*)d_out;                 // [2,2048,1024]
  float* att = out + 4194304;                 // [2,16,2048,2048]

  char* ws = (char*)d_ws;
  unsigned short* xb  = (unsigned short*)(ws);             //  8 MB
  unsigned short* wqt = (unsigned short*)(ws + 8388608);   //  2 MB
  unsigned short* wkt = (unsigned short*)(ws + 10485760);
  unsigned short* wvt = (unsigned short*)(ws + 12582912);
  unsigned short* wpt = (unsigned short*)(ws + 14680064);
  unsigned short* Qw  = (unsigned short*)(ws + 16777216);  //  8 MB [b,h,t,d]
  unsigned short* Kw  = (unsigned short*)(ws + 25165824);  //  8 MB [b,h,t,d]
  unsigned short* Vtw = (unsigned short*)(ws + 33554432);  //  8 MB [b,h,d,t]
  unsigned short* ctx = (unsigned short*)(ws + 41943040);  //  8 MB [b,t,D]
  float* madd         = (float*)(ws + 50331648);           // 16 KB

  k_convert_x<<<4096, 256, 0, stream>>>(x, xb);
  k_mask<<<16, 256, 0, stream>>>(mask, madd);
  k_transpose_w<<<1024, 256, 0, stream>>>(wq, wk, wv, wp, wqt, wkt, wvt, wpt);
  k_gemm_qkv<<<dim3(32, 24), 256, 0, stream>>>(xb, wqt, wkt, wvt, bq, bk, bv, Qw, Kw, Vtw);
  k_attn<<<1024, 256, 0, stream>>>(Qw, Kw, Vtw, madd, att, ctx);
  k_gemm_proj<<<dim3(32, 8), 256, 0, stream>>>(ctx, wpt, bp, out);
}